// Round 4
// baseline (72.075 us; speedup 1.0000x reference)
//
#include <hip/hip_runtime.h>

#define BATCH 512
#define KBITS 14
#define TABLE 16384

// ---------------------------------------------------------------------------
// Layout: activation rows are bit-packed transposed: row r = 64 bytes,
// byte t holds batches t*8 .. t*8+7 (bit j = batch t*8+j).
// ---------------------------------------------------------------------------

// Fused transpose + bit-pack for BOTH x and state in one launch.
// Blocks 0..127: x [512][1024] -> xP [1024][64].
// Blocks 128..383: state [512][2048] -> stP [2048][64].
__global__ __launch_bounds__(256)
void prep(const int* __restrict__ x, const int* __restrict__ st,
          unsigned char* __restrict__ xP, unsigned char* __restrict__ stP) {
    __shared__ unsigned char lds[64 * 65];
    const int bid = blockIdx.x;
    const int* in;
    unsigned char* out;
    int C, tile;
    if (bid < 128) { in = x;  out = xP;  C = 1024; tile = bid; }
    else           { in = st; out = stP; C = 2048; tile = bid - 128; }
    const int tilesx = C >> 6;
    const int c0 = (tile % tilesx) * 64;
    const int b0 = (tile / tilesx) * 64;
    const int t = threadIdx.x;

#pragma unroll
    for (int i = 0; i < 16; ++i) {
        int flat = i * 256 + t;          // 0..4095
        int brow = flat >> 6;            // batch offset 0..63
        int ccol = flat & 63;            // col offset 0..63
        lds[ccol * 65 + brow] = (unsigned char)(in[(size_t)(b0 + brow) * C + (c0 + ccol)] & 1);
    }
    __syncthreads();

    const int c = t >> 2;                // 0..63
    const int q = t & 3;                 // bytes 2q, 2q+1
#pragma unroll
    for (int jj = 0; jj < 2; ++jj) {
        int j = q * 2 + jj;
        unsigned int byte = 0;
#pragma unroll
        for (int i = 0; i < 8; ++i)
            byte |= ((unsigned int)lds[c * 65 + j * 8 + i] & 1u) << i;
        out[(size_t)(c0 + c) * 64 + (b0 >> 3) + j] = (unsigned char)byte;
    }
}

// One wave (64 lanes) = one neuron; lane t handles batches t*8 .. t*8+7.
// If out_i32 != nullptr (layer 3), scatter int32 results to [B][N] directly
// instead of writing the packed row.
__global__ __launch_bounds__(128)
void ram_layer_p(const unsigned char* __restrict__ in0,  // packed rows, c < split
                 const unsigned char* __restrict__ in1,  // packed rows, c >= split (index c-split)
                 int split,
                 const int* __restrict__ conn,           // [N][14]
                 const int* __restrict__ mem,            // [N][16384] int32 0/1
                 unsigned char* __restrict__ outP,       // [N][64] packed (if out_i32 == nullptr)
                 int* __restrict__ out_i32,              // [512][N_total] or nullptr
                 int n_total)
{
    const int n = blockIdx.x * 2 + (threadIdx.x >> 6);
    const int t = threadIdx.x & 63;
    const int* cp = conn + n * KBITS;    // wave-uniform -> scalar loads

    unsigned char w[KBITS];
#pragma unroll
    for (int k = 0; k < KBITS; ++k) {
        int c = cp[k];
        const unsigned char* row = (c < split) ? (in0 + (size_t)c * 64)
                                               : (in1 + (size_t)(c - split) * 64);
        w[k] = row[t];                   // wave reads one 64-byte line
    }

    unsigned int a[8] = {0, 0, 0, 0, 0, 0, 0, 0};
#pragma unroll
    for (int k = 0; k < KBITS; ++k) {
#pragma unroll
        for (int j = 0; j < 8; ++j)
            a[j] |= (((unsigned int)w[k] >> j) & 1u) << k;
    }

    const int* m = mem + (size_t)n * TABLE;
    int r[8];
#pragma unroll
    for (int j = 0; j < 8; ++j) r[j] = m[a[j]];   // 8 independent random loads

    if (out_i32) {
        // Layer 3: write int32 output directly. 8 scattered dword stores per
        // lane; every 64B output line is fully covered across waves -> merges
        // to ~4 MB of write traffic.
#pragma unroll
        for (int j = 0; j < 8; ++j)
            out_i32[(size_t)(t * 8 + j) * n_total + n] = r[j] & 1;
    } else {
        unsigned int res = 0;
#pragma unroll
        for (int j = 0; j < 8; ++j) res |= ((unsigned int)r[j] & 1u) << j;
        outP[(size_t)n * 64 + t] = (unsigned char)res;
    }
}

extern "C" void kernel_launch(void* const* d_in, const int* in_sizes, int n_in,
                              void* d_out, int out_size, void* d_ws, size_t ws_size,
                              hipStream_t stream) {
    const int* x        = (const int*)d_in[0];  // [512][1024] int32 0/1
    const int* state    = (const int*)d_in[1];  // [512][2048] int32 0/1
    const int* in_conn  = (const int*)d_in[2];  // [4096][14]
    const int* st_conn  = (const int*)d_in[3];  // [2048][14]
    const int* out_conn = (const int*)d_in[4];  // [2048][14]
    const int* in_mem   = (const int*)d_in[5];  // [4096][16384]
    const int* st_mem   = (const int*)d_in[6];  // [2048][16384]
    const int* out_mem  = (const int*)d_in[7];  // [2048][16384]
    int* out = (int*)d_out;

    unsigned char* ws  = (unsigned char*)d_ws;
    unsigned char* xP  = ws;                    // [1024][64] =  64 KiB
    unsigned char* hsP = ws + (64 << 10);       // [6144][64] = 384 KiB (rows 0..4095 = h, 4096..6143 = state)
    unsigned char* sP  = ws + (448 << 10);      // [2048][64] = 128 KiB

    // Transpose + bit-pack x and state (one launch).
    prep<<<384, 256, 0, stream>>>(x, state, xP, hsP + (size_t)4096 * 64);

    // Layer 1: h = in_mem[x-addr]; writes hsP rows 0..4095.
    ram_layer_p<<<4096 / 2, 128, 0, stream>>>(xP, xP, 1 << 30, in_conn, in_mem,
                                              hsP, nullptr, 0);
    // Layer 2: s = st_mem[cat(h,state)-addr]; all 6144 rows live in hsP.
    ram_layer_p<<<2048 / 2, 128, 0, stream>>>(hsP, hsP, 1 << 30, st_conn, st_mem,
                                              sP, nullptr, 0);
    // Layer 3: out = out_mem[cat(h,s)-addr]; fused int32 output write.
    ram_layer_p<<<2048 / 2, 128, 0, stream>>>(hsP, sP, 4096, out_conn, out_mem,
                                              nullptr, out, 2048);
}

// Round 5
// 63.212 us; speedup vs baseline: 1.1402x; 1.1402x over previous
//
#include <hip/hip_runtime.h>

#define BATCH 512
#define KBITS 14
#define TABLE 16384

// ---------------------------------------------------------------------------
// Layout: activation rows are bit-packed transposed: row r = 64 bytes,
// byte t holds batches t*8 .. t*8+7 (bit j = batch t*8+j).
// ---------------------------------------------------------------------------

// Fused transpose + bit-pack for BOTH x and state in one launch.
// Blocks 0..127: x [512][1024] -> xP [1024][64].
// Blocks 128..383: state [512][2048] -> stP [2048][64].
__global__ __launch_bounds__(256)
void prep(const int* __restrict__ x, const int* __restrict__ st,
          unsigned char* __restrict__ xP, unsigned char* __restrict__ stP) {
    __shared__ unsigned char lds[64 * 65];
    const int bid = blockIdx.x;
    const int* in;
    unsigned char* out;
    int C, tile;
    if (bid < 128) { in = x;  out = xP;  C = 1024; tile = bid; }
    else           { in = st; out = stP; C = 2048; tile = bid - 128; }
    const int tilesx = C >> 6;
    const int c0 = (tile % tilesx) * 64;
    const int b0 = (tile / tilesx) * 64;
    const int t = threadIdx.x;

#pragma unroll
    for (int i = 0; i < 16; ++i) {
        int flat = i * 256 + t;          // 0..4095
        int brow = flat >> 6;            // batch offset 0..63
        int ccol = flat & 63;            // col offset 0..63
        lds[ccol * 65 + brow] = (unsigned char)(in[(size_t)(b0 + brow) * C + (c0 + ccol)] & 1);
    }
    __syncthreads();

    const int c = t >> 2;                // 0..63
    const int q = t & 3;                 // bytes 2q, 2q+1
#pragma unroll
    for (int jj = 0; jj < 2; ++jj) {
        int j = q * 2 + jj;
        unsigned int byte = 0;
#pragma unroll
        for (int i = 0; i < 8; ++i)
            byte |= ((unsigned int)lds[c * 65 + j * 8 + i] & 1u) << i;
        out[(size_t)(c0 + c) * 64 + (b0 >> 3) + j] = (unsigned char)byte;
    }
}

// One wave (64 lanes) = one neuron; lane t handles batches t*8 .. t*8+7.
// Gathers are one 64-byte line per wave; 8 independent table loads in flight;
// output is the packed row (64 coalesced bytes per wave).
__global__ __launch_bounds__(128)
void ram_layer_p(const unsigned char* __restrict__ in0,  // packed rows, c < split
                 const unsigned char* __restrict__ in1,  // packed rows, c >= split (index c-split)
                 int split,
                 const int* __restrict__ conn,           // [N][14]
                 const int* __restrict__ mem,            // [N][16384] int32 0/1
                 unsigned char* __restrict__ outP)       // [N][64] packed
{
    const int n = blockIdx.x * 2 + (threadIdx.x >> 6);
    const int t = threadIdx.x & 63;
    const int* cp = conn + n * KBITS;    // same addr across wave -> broadcast

    unsigned char w[KBITS];
#pragma unroll
    for (int k = 0; k < KBITS; ++k) {
        int c = cp[k];
        const unsigned char* row = (c < split) ? (in0 + (size_t)c * 64)
                                               : (in1 + (size_t)(c - split) * 64);
        w[k] = row[t];                   // wave reads one 64-byte line
    }

    unsigned int a[8] = {0, 0, 0, 0, 0, 0, 0, 0};
#pragma unroll
    for (int k = 0; k < KBITS; ++k) {
#pragma unroll
        for (int j = 0; j < 8; ++j)
            a[j] |= (((unsigned int)w[k] >> j) & 1u) << k;
    }

    const int* m = mem + (size_t)n * TABLE;
    int r[8];
#pragma unroll
    for (int j = 0; j < 8; ++j) r[j] = m[a[j]];   // 8 independent random loads

    unsigned int res = 0;
#pragma unroll
    for (int j = 0; j < 8; ++j) res |= ((unsigned int)r[j] & 1u) << j;
    outP[(size_t)n * 64 + t] = (unsigned char)res;
}

// Unpack [2048][64] packed output to int32 [512][2048] with int4 stores.
// Thread handles 4 consecutive n for one b: reads 4 L1-resident bytes,
// writes 16 coalesced bytes.
__global__ __launch_bounds__(256)
void out_convert_p(const unsigned char* __restrict__ oP, int* __restrict__ out) {
    int idx = blockIdx.x * blockDim.x + threadIdx.x;  // idx = (b*2048 + n0)/4
    int b = idx >> 9;                  // /512  (512 groups of 4 per batch row)
    int n0 = (idx & 511) << 2;
    int byte = b >> 3, bit = b & 7;
    int4 v;
    v.x = (oP[(size_t)(n0 + 0) * 64 + byte] >> bit) & 1;
    v.y = (oP[(size_t)(n0 + 1) * 64 + byte] >> bit) & 1;
    v.z = (oP[(size_t)(n0 + 2) * 64 + byte] >> bit) & 1;
    v.w = (oP[(size_t)(n0 + 3) * 64 + byte] >> bit) & 1;
    *(int4*)(out + (size_t)b * 2048 + n0) = v;
}

extern "C" void kernel_launch(void* const* d_in, const int* in_sizes, int n_in,
                              void* d_out, int out_size, void* d_ws, size_t ws_size,
                              hipStream_t stream) {
    const int* x        = (const int*)d_in[0];  // [512][1024] int32 0/1
    const int* state    = (const int*)d_in[1];  // [512][2048] int32 0/1
    const int* in_conn  = (const int*)d_in[2];  // [4096][14]
    const int* st_conn  = (const int*)d_in[3];  // [2048][14]
    const int* out_conn = (const int*)d_in[4];  // [2048][14]
    const int* in_mem   = (const int*)d_in[5];  // [4096][16384]
    const int* st_mem   = (const int*)d_in[6];  // [2048][16384]
    const int* out_mem  = (const int*)d_in[7];  // [2048][16384]
    int* out = (int*)d_out;

    unsigned char* ws  = (unsigned char*)d_ws;
    unsigned char* xP  = ws;                    // [1024][64] =  64 KiB
    unsigned char* hsP = ws + (64 << 10);       // [6144][64] = 384 KiB (rows 0..4095 = h, 4096..6143 = state)
    unsigned char* sP  = ws + (448 << 10);      // [2048][64] = 128 KiB
    unsigned char* oP  = ws + (576 << 10);      // [2048][64] = 128 KiB

    // Transpose + bit-pack x and state (one launch).
    prep<<<384, 256, 0, stream>>>(x, state, xP, hsP + (size_t)4096 * 64);

    // Layer 1: h = in_mem[x-addr]; writes hsP rows 0..4095.
    ram_layer_p<<<4096 / 2, 128, 0, stream>>>(xP, xP, 1 << 30, in_conn, in_mem, hsP);
    // Layer 2: s = st_mem[cat(h,state)-addr]; all 6144 rows live in hsP.
    ram_layer_p<<<2048 / 2, 128, 0, stream>>>(hsP, hsP, 1 << 30, st_conn, st_mem, sP);
    // Layer 3: out = out_mem[cat(h,s)-addr]; packed output.
    ram_layer_p<<<2048 / 2, 128, 0, stream>>>(hsP, sP, 4096, out_conn, out_mem, oP);

    // Unpack to int32 [512][2048].
    out_convert_p<<<(BATCH * 2048 / 4) / 256, 256, 0, stream>>>(oP, out);
}